// Round 1
// baseline (13430.351 us; speedup 1.0000x reference)
//
#include <hip/hip_runtime.h>

// Problem dims (fixed)
constexpr int BATCH = 64;
constexpr int SEQ   = 512;
constexpr int DIN   = 512;
constexpr int HID   = 512;
constexpr int LAY   = 2;
constexpr int G3    = 3 * HID;   // 1536

constexpr int NSLICE = 16;       // WGs per (layer,dir) cell
constexpr int WSLICE = 32;       // hidden columns per WG
constexpr int NTHR   = 512;      // 8 waves per WG
constexpr int CNTPAD = 1024;     // u32 stride between cell counters (4 KB apart)

typedef __attribute__((ext_vector_type(8))) short bf16x8;  // MFMA A/B frag (4 VGPRs)
typedef __attribute__((ext_vector_type(4))) float f32x4;   // MFMA C/D frag
typedef unsigned short u16;
typedef unsigned int   u32;
typedef unsigned long long u64;

__device__ __forceinline__ u16 f2bf(float f) {
  union { float f; u32 u; } v; v.f = f;
  return (u16)((v.u + 0x7fffu + ((v.u >> 16) & 1u)) >> 16);  // RNE
}

// Agent-scope RELAXED accesses: coherent at LLC (bypass non-coherent per-XCD
// L2), no cache-maintenance ops (no buffer_inv / wbl2). Visibility protocol:
// producer stores are drained (vmcnt 0) by __syncthreads before thread 0's
// counter add; LLC is the single serialization point; consumers' payload
// loads issue after the poll branch + s_barrier release.
__device__ __forceinline__ u64 ld_agent_u64(const u16* p) {
  return __hip_atomic_load((const u64*)p, __ATOMIC_RELAXED, __HIP_MEMORY_SCOPE_AGENT);
}
__device__ __forceinline__ bf16x8 ld_frag_agent(const u16* p) {
  union { u64 q[2]; bf16x8 f; } u;
  u.q[0] = ld_agent_u64(p);
  u.q[1] = ld_agent_u64(p + 4);
  return u.f;
}
__device__ __forceinline__ void st_agent_u16(u16* p, u16 v) {
  __hip_atomic_store(p, v, __ATOMIC_RELAXED, __HIP_MEMORY_SCOPE_AGENT);
}

// Single-wave poll of one aggregate counter (all lanes load the same 4B word
// -> one coalesced request). Executed by wave 0 only; others wait at barrier.
__device__ __forceinline__ void poll1(const u32* c, u32 target) {
  for (;;) {
    u32 v = __hip_atomic_load(c, __ATOMIC_RELAXED, __HIP_MEMORY_SCOPE_AGENT);
    if (v >= target) break;
    __builtin_amdgcn_s_sleep(1);
  }
  __asm__ volatile("" ::: "memory");  // keep subsequent loads after the poll
}

struct Params {
  const float* input;     // [BATCH][SEQ][DIN]
  const float* enc_h;     // [LAY][BATCH][2*HID]
  const float* Wih[2];    // dir f/b: [LAY][G3][DIN]
  const float* Whh[2];    // [LAY][G3][HID]
  const float* bih[2];    // [LAY][G3]
  const float* bhh[2];    // [LAY][G3]
  float* out;             // [BATCH][SEQ][2H] ++ [LAY][BATCH][2H]
  u16* xin;               // [BATCH][SEQ][DIN] bf16
  u16* wih;               // [2dir][LAY][G3][DIN] bf16
  u16* whh;               // [2dir][LAY][G3][HID] bf16
  u16* out0;              // [2dir][SEQ][BATCH][HID] bf16 layer-0 outputs (scan order)
  u16* hbf;               // [LAY][2 parity][2 dir][BATCH][HID] bf16 h broadcast
  u32* cnt;               // [4 cells] aggregate step counters, 4KB apart
};

__global__ __launch_bounds__(256) void convert_kernel(Params p) {
  const int gtid = blockIdx.x * 256 + threadIdx.x;
  const int nthr = gridDim.x * 256;
  for (int i = gtid; i < BATCH * SEQ * DIN; i += nthr) p.xin[i] = f2bf(p.input[i]);
  for (int d = 0; d < 2; ++d) {
    const float* s1 = p.Wih[d];
    u16* d1 = p.wih + (size_t)d * LAY * G3 * DIN;
    for (int i = gtid; i < LAY * G3 * DIN; i += nthr) d1[i] = f2bf(s1[i]);
    const float* s2 = p.Whh[d];
    u16* d2 = p.whh + (size_t)d * LAY * G3 * HID;
    for (int i = gtid; i < LAY * G3 * HID; i += nthr) d2[i] = f2bf(s2[i]);
  }
  if (gtid < 4 * CNTPAD) p.cnt[gtid] = 0;
}

// 64 WGs x 512 threads. wg&3 = cell (layer*2+dir), wg>>2 = 32-wide hidden
// slice (16 slices/cell). 8 waves: wave&3 = batch m-tile of 16, wave>>2 =
// 16-col n-tile within the slice. h master fp32 in regs; bf16 double-buffered
// broadcast via LLC (agent ops). Whh slice LDS-resident (aligned + XOR-
// swizzled, conflict-free). Per-step sync = one atomicAdd per WG + one 4B
// counter poll by wave 0. x-GEMM loads issue before the own-poll (latency
// hides under the poll); h-frags for t+1 prefetched into regs after it.
__global__ __launch_bounds__(NTHR, 1) void recur_all(Params p) {
  const int wg    = blockIdx.x;     // 0..63
  const int cell  = wg & 3;         // layer*2 + dir
  const int layer = cell >> 1;
  const int dir   = cell & 1;
  const int slice = wg >> 2;        // 0..15
  const int j0    = slice * WSLICE;

  const int wave = threadIdx.x >> 6;
  const int lane = threadIdx.x & 63;
  const int lq = lane >> 4, ln = lane & 15;
  const int mt = wave & 3, nt = wave >> 2;
  const int am = mt * 16 + ln;      // A-frag row (batch index)
  const int rr = nt * 16 + ln;      // B row within this WG's slice
  const int j  = j0 + rr;           // global hidden column for this lane

  // ---- stage Whh slice into LDS: [gate][jj][k], rows 1024B (16B aligned),
  // 16B units XOR-swizzled by row (T2) -> conflict-free ds_read_b128 ----
  __shared__ u16 lwhh[3][WSLICE][512];   // 98,304 B
  {
    const u16* whh = p.whh + ((size_t)dir * LAY + layer) * G3 * HID;
    for (int idx = threadIdx.x; idx < 3 * WSLICE * 64; idx += NTHR) {
      const int k8 = idx & 63, row = idx >> 6;     // row = g*32+jj
      const int g = row >> 5, jj = row & 31;
      *(bf16x8*)&lwhh[g][jj][(k8 ^ (jj & 7)) * 8] =
          *(const bf16x8*)(whh + (size_t)(g * HID + j0 + jj) * HID + k8 * 8);
    }
  }

  u16* hbL = p.hbf + (size_t)layer * 2 * 2 * BATCH * HID;
  u16* hb0 = hbL + (size_t)dir * BATCH * HID;            // parity 0
  u16* hb1 = hbL + (size_t)(2 + dir) * BATCH * HID;      // parity 1

  const u16* wih = p.wih + ((size_t)dir * LAY + layer) * G3 * DIN;
  const u16* bri[3];
  #pragma unroll
  for (int g = 0; g < 3; ++g) bri[g] = wih + (size_t)(g * HID + j) * DIN;

  const float* bih = p.bih[dir] + (size_t)layer * G3;
  const float* bhh = p.bhh[dir] + (size_t)layer * G3;
  const float b_r  = bih[j] + bhh[j];
  const float b_z  = bih[HID + j] + bhh[HID + j];
  const float bi_n = bih[2 * HID + j];
  const float bh_n = bhh[2 * HID + j];

  // init h (fp32 master) + bf16 broadcast into parity 0 (agent-scope)
  float hreg[4];
  #pragma unroll
  for (int i = 0; i < 4; ++i) {
    const int m = mt * 16 + lq * 4 + i;           // C/D row = (lane>>4)*4 + reg
    hreg[i] = p.enc_h[((size_t)layer * BATCH + m) * (2 * HID) + (size_t)dir * HID + j];
    st_agent_u16(&hb0[(size_t)m * HID + j], f2bf(hreg[i]));
  }

  u32* own = p.cnt + (size_t)cell * CNTPAD;
  u32* dep = p.cnt + (size_t)dir  * CNTPAD;       // layer-0 cell, same dir
  // Counter protocol: each WG adds 1 after init and after each step t.
  // cnt == NSLICE*(t+2)  <=>  all 16 WGs finished step t (h_{t+1}, out0[t]
  // visible at LLC). Monotonic, >= polls, no deadlock.

  __threadfence_block();   // belt+suspenders: __syncthreads drains vmcnt/lgkm
  __syncthreads();
  if (threadIdx.x == 0)
    __hip_atomic_fetch_add(own, 1u, __ATOMIC_RELAXED, __HIP_MEMORY_SCOPE_AGENT);

  float* hsec = p.out + (size_t)BATCH * SEQ * 2 * HID;

  bf16x8 fr[16];           // payload frags (x, then h) - fully static indexing
  f32x4  accx[3];

  // ---- step 0: issue x loads, poll under them, x-GEMM, prefetch h0 ----
  if (layer == 1) { if (wave == 0) poll1(dep, 2 * NSLICE); __syncthreads(); }
  {
    const u16* ax = (layer == 0)
        ? p.xin + ((size_t)am * SEQ + (dir ? SEQ - 1 : 0)) * DIN
        : p.out0 + ((size_t)dir * SEQ * BATCH + am) * HID;
    if (layer == 0) {
      #pragma unroll
      for (int kk = 0; kk < 16; ++kk) fr[kk] = *(const bf16x8*)(ax + kk * 32 + lq * 8);
    } else {
      #pragma unroll
      for (int kk = 0; kk < 16; ++kk) fr[kk] = ld_frag_agent(ax + kk * 32 + lq * 8);
    }
  }
  if (wave == 0) poll1(own, NSLICE);   // h_0 broadcast visible
  __syncthreads();
  accx[0] = f32x4{0.f, 0.f, 0.f, 0.f}; accx[1] = accx[0]; accx[2] = accx[0];
  #pragma unroll
  for (int kk = 0; kk < 16; ++kk) {
    #pragma unroll
    for (int g = 0; g < 3; ++g)
      accx[g] = __builtin_amdgcn_mfma_f32_16x16x32_bf16(
          fr[kk], *(const bf16x8*)(bri[g] + kk * 32 + lq * 8), accx[g], 0, 0, 0);
  }
  {
    const u16* ah = hb0 + (size_t)am * HID;
    #pragma unroll
    for (int kk = 0; kk < 16; ++kk) fr[kk] = ld_frag_agent(ah + kk * 32 + lq * 8);
  }

  for (int t = 0; t < SEQ; ++t) {
    // ---- h-GEMM (critical path): A from regs, B from swizzled LDS ----
    f32x4 acch[3];
    acch[0] = f32x4{0.f, 0.f, 0.f, 0.f}; acch[1] = acch[0]; acch[2] = acch[0];
    #pragma unroll
    for (int kk = 0; kk < 16; ++kk) {
      #pragma unroll
      for (int g = 0; g < 3; ++g)
        acch[g] = __builtin_amdgcn_mfma_f32_16x16x32_bf16(
            fr[kk],
            *(const bf16x8*)&lwhh[g][rr][(((kk << 2) + lq) ^ (rr & 7)) * 8],
            acch[g], 0, 0, 0);
    }

    // ---- gate epilogue + stores ----
    u16* hwrite = ((t + 1) & 1) ? hb1 : hb0;
    #pragma unroll
    for (int i = 0; i < 4; ++i) {
      const int m = mt * 16 + lq * 4 + i;
      const float r = 1.f / (1.f + __expf(-(accx[0][i] + acch[0][i] + b_r)));
      const float z = 1.f / (1.f + __expf(-(accx[1][i] + acch[1][i] + b_z)));
      const float n = tanhf(accx[2][i] + bi_n + r * (acch[2][i] + bh_n));
      const float hnew = (1.f - z) * n + z * hreg[i];
      hreg[i] = hnew;
      if (t + 1 < SEQ) st_agent_u16(&hwrite[(size_t)m * HID + j], f2bf(hnew));
      if (layer == 0) {
        st_agent_u16(&p.out0[(((size_t)dir * SEQ + t) * BATCH + m) * HID + j], f2bf(hnew));
      } else {
        const int tt = dir ? (SEQ - 1 - t) : t;
        p.out[((size_t)m * SEQ + tt) * (2 * HID) + (size_t)dir * HID + j] = hnew;
      }
      if (t == SEQ - 1)
        hsec[((size_t)layer * BATCH + m) * (2 * HID) + (size_t)dir * HID + j] = hnew;
    }

    // ---- signal: all WG stores drained by the barrier, then one add ----
    __threadfence_block();
    __syncthreads();
    if (threadIdx.x == 0)
      __hip_atomic_fetch_add(own, 1u, __ATOMIC_RELAXED, __HIP_MEMORY_SCOPE_AGENT);

    if (t + 1 < SEQ) {
      const int tn = t + 1;
      // layer 1: wait for out0[tn] (layer-0 step tn done)
      if (layer == 1) { if (wave == 0) poll1(dep, (u32)(NSLICE * (tn + 2))); __syncthreads(); }
      // issue x loads for t+1 (latency hides under the own-poll below)
      const u16* ax = (layer == 0)
          ? p.xin + ((size_t)am * SEQ + (dir ? SEQ - 1 - tn : tn)) * DIN
          : p.out0 + (((size_t)dir * SEQ + tn) * BATCH + am) * HID;
      if (layer == 0) {
        #pragma unroll
        for (int kk = 0; kk < 16; ++kk) fr[kk] = *(const bf16x8*)(ax + kk * 32 + lq * 8);
      } else {
        #pragma unroll
        for (int kk = 0; kk < 16; ++kk) fr[kk] = ld_frag_agent(ax + kk * 32 + lq * 8);
      }
      if (wave == 0) poll1(own, (u32)(NSLICE * (t + 2)));  // h_{t+1} visible
      __syncthreads();
      // x-GEMM for t+1
      accx[0] = f32x4{0.f, 0.f, 0.f, 0.f}; accx[1] = accx[0]; accx[2] = accx[0];
      #pragma unroll
      for (int kk = 0; kk < 16; ++kk) {
        #pragma unroll
        for (int g = 0; g < 3; ++g)
          accx[g] = __builtin_amdgcn_mfma_f32_16x16x32_bf16(
              fr[kk], *(const bf16x8*)(bri[g] + kk * 32 + lq * 8), accx[g], 0, 0, 0);
      }
      // prefetch h_{t+1} frags into regs (consumed at next loop top)
      const u16* ah = ((tn & 1) ? hb1 : hb0) + (size_t)am * HID;
      #pragma unroll
      for (int kk = 0; kk < 16; ++kk) fr[kk] = ld_frag_agent(ah + kk * 32 + lq * 8);
    }
  }
}

extern "C" void kernel_launch(void* const* d_in, const int* in_sizes, int n_in,
                              void* d_out, int out_size, void* d_ws, size_t ws_size,
                              hipStream_t stream) {
  Params p;
  p.input  = (const float*)d_in[0];
  p.enc_h  = (const float*)d_in[1];
  p.Wih[0] = (const float*)d_in[2];
  p.Whh[0] = (const float*)d_in[3];
  p.bih[0] = (const float*)d_in[4];
  p.bhh[0] = (const float*)d_in[5];
  p.Wih[1] = (const float*)d_in[6];
  p.Whh[1] = (const float*)d_in[7];
  p.bih[1] = (const float*)d_in[8];
  p.bhh[1] = (const float*)d_in[9];
  p.out = (float*)d_out;

  uintptr_t base = (uintptr_t)d_ws;
  size_t off = 0;
  auto take = [&](size_t bytes) -> void* {
    void* r = (void*)(base + off);
    off += (bytes + 255) & ~(size_t)255;
    return r;
  };
  p.xin   = (u16*)take((size_t)BATCH * SEQ * DIN * 2);        // 33.6 MB
  p.wih   = (u16*)take((size_t)2 * LAY * G3 * DIN * 2);       //  6.3 MB
  p.whh   = (u16*)take((size_t)2 * LAY * G3 * HID * 2);       //  6.3 MB
  p.out0  = (u16*)take((size_t)2 * SEQ * BATCH * HID * 2);    // 67.1 MB
  p.hbf   = (u16*)take((size_t)LAY * 2 * 2 * BATCH * HID * 2);//  1.0 MB
  p.cnt   = (u32*)take((size_t)4 * CNTPAD * 4);               //   16 KB
  if (off > ws_size) return;  // ~114 MB required (same budget as before)

  convert_kernel<<<dim3(2048), dim3(256), 0, stream>>>(p);
  recur_all<<<dim3(64), dim3(NTHR), 0, stream>>>(p);
}

// Round 2
// 11881.667 us; speedup vs baseline: 1.1303x; 1.1303x over previous
//
#include <hip/hip_runtime.h>

// Problem dims (fixed)
constexpr int BATCH = 64;
constexpr int SEQ   = 512;
constexpr int DIN   = 512;
constexpr int HID   = 512;
constexpr int LAY   = 2;
constexpr int G3    = 3 * HID;   // 1536
constexpr int KPAD  = 522;       // odd dword stride (261) -> conflict-free LDS rows

typedef __attribute__((ext_vector_type(8))) short bf16x8;  // MFMA A/B frag (4 VGPRs)
typedef __attribute__((ext_vector_type(4))) float f32x4;   // MFMA C/D frag
typedef unsigned short u16;
typedef unsigned int   u32;
typedef unsigned long long u64;

__device__ __forceinline__ u16 f2bf(float f) {
  union { float f; u32 u; } v; v.f = f;
  return (u16)((v.u + 0x7fffu + ((v.u >> 16) & 1u)) >> 16);  // RNE
}

// Agent-scope RELAXED accesses: coherent at LLC (bypass non-coherent per-XCD
// L2), no cache maintenance (no buffer_inv / buffer_wbl2). Visibility:
// producer's agent stores drained (vmcnt 0) by __syncthreads before the flag
// store; LLC is the single serialization point; consumer's loads issue after
// its poll branch resolves.
__device__ __forceinline__ u64 ld_agent_u64(const u16* p) {
  return __hip_atomic_load((const u64*)p, __ATOMIC_RELAXED, __HIP_MEMORY_SCOPE_AGENT);
}
__device__ __forceinline__ bf16x8 ld_frag_agent(const u16* p) {
  union { u64 q[2]; bf16x8 f; } u;
  u.q[0] = ld_agent_u64(p);
  u.q[1] = ld_agent_u64(p + 4);
  return u.f;
}
__device__ __forceinline__ void st_agent_u16(u16* p, u16 v) {
  __hip_atomic_store(p, v, __ATOMIC_RELAXED, __HIP_MEMORY_SCOPE_AGENT);
}
__device__ __forceinline__ void st_agent_u32(u32* p, u32 v) {
  __hip_atomic_store(p, v, __ATOMIC_RELAXED, __HIP_MEMORY_SCOPE_AGENT);
}

// Poll all 32 flags of a cell (one coalesced 128B load) until min >= target.
// All waves poll (proven structure).
__device__ __forceinline__ void poll_ge(const u32* flags, u32 target) {
  const int idx = threadIdx.x & 31;
  for (;;) {
    u32 v = __hip_atomic_load(flags + idx, __ATOMIC_RELAXED, __HIP_MEMORY_SCOPE_AGENT);
    #pragma unroll
    for (int off = 16; off >= 1; off >>= 1) {
      u32 o = (u32)__shfl_xor((int)v, off, 64);
      v = v < o ? v : o;
    }
    if (v >= target) break;
    __builtin_amdgcn_s_sleep(1);
  }
  __asm__ volatile("" ::: "memory");  // keep subsequent loads after the poll
}

struct Params {
  const float* input;     // [BATCH][SEQ][DIN]
  const float* enc_h;     // [LAY][BATCH][2*HID]
  const float* Wih[2];    // dir f/b: [LAY][G3][DIN]
  const float* Whh[2];    // [LAY][G3][HID]
  const float* bih[2];    // [LAY][G3]
  const float* bhh[2];    // [LAY][G3]
  float* out;             // [BATCH][SEQ][2H] ++ [LAY][BATCH][2H]
  u16* xin;               // [BATCH][SEQ][DIN] bf16
  u16* wih;               // [2dir][LAY][G3][DIN] bf16
  u16* whh;               // [2dir][LAY][G3][HID] bf16
  u16* hbf;               // [LAY][2 parity][2 dir][BATCH][HID] bf16 h broadcast
  u32* flags;             // [2 dir][32] per-WG iteration flags
};

__global__ __launch_bounds__(256) void convert_kernel(Params p) {
  const int gtid = blockIdx.x * 256 + threadIdx.x;
  const int nthr = gridDim.x * 256;
  for (int i = gtid; i < BATCH * SEQ * DIN; i += nthr) p.xin[i] = f2bf(p.input[i]);
  for (int d = 0; d < 2; ++d) {
    const float* s1 = p.Wih[d];
    u16* d1 = p.wih + (size_t)d * LAY * G3 * DIN;
    for (int i = gtid; i < LAY * G3 * DIN; i += nthr) d1[i] = f2bf(s1[i]);
    const float* s2 = p.Whh[d];
    u16* d2 = p.whh + (size_t)d * LAY * G3 * HID;
    for (int i = gtid; i < LAY * G3 * HID; i += nthr) d2[i] = f2bf(s2[i]);
  }
  if (gtid < 2 * 32) p.flags[gtid] = 0;
}

// 64 WGs x 256 thr: wg&1 = dir, wg>>1 = 16-wide hidden slice (32/cell).
// Each WG covers the FULL batch (4 waves x 16 rows) and BOTH layers:
// iteration i computes L0 step i (i<SEQ) and L1 step i-1 (i>=1), SEQ+1 iters.
// L1's x input out0[i-1] IS the h0 broadcast at parity i&1 -> the h0 A-frags
// feed both the L0 h-GEMM and the L1 x-GEMM (loaded once). No out0 array,
// no layer-dep poll: ONE poll + ONE payload load per iteration.
// x0-GEMM for iter i+1 runs in the barrier shadow (signal->poll), as proven.
__global__ __launch_bounds__(256, 1) void recur_all(Params p) {
  const int wg    = blockIdx.x;     // 0..63
  const int dir   = wg & 1;
  const int slice = wg >> 1;        // 0..31
  const int j0    = slice * 16;
  const int wave  = threadIdx.x >> 6;
  const int lane  = threadIdx.x & 63;
  const int lq = lane >> 4, ln = lane & 15;
  const int j  = j0 + ln;           // hidden column (C/D col = lane&15)
  const int am = wave * 16 + ln;    // A-frag row (batch index)

  // ---- stage BOTH layers' Whh slices into LDS (proven KPAD layout) ----
  __shared__ u16 lwhh[LAY][3][16][KPAD];   // 100,224 B
  {
    const u16* whh = p.whh + (size_t)dir * LAY * G3 * HID;
    for (int idx = threadIdx.x; idx < LAY * 3 * 16 * 64; idx += 256) {
      const int k8 = idx & 63, row = idx >> 6;     // row = lay*48 + g*16 + jj
      const int lay = row >= 48;
      const int rem = row - lay * 48;
      const int g = rem >> 4, jj = rem & 15;
      *(bf16x8*)&lwhh[lay][g][jj][k8 * 8] =
          *(const bf16x8*)(whh + ((size_t)lay * G3 + (size_t)(g * HID + j0 + jj)) * HID + k8 * 8);
    }
  }

  // h broadcast buffers: [layer][parity][dir][BATCH][HID]
  u16* h0b[2], * h1b[2];
  #pragma unroll
  for (int par = 0; par < 2; ++par) {
    h0b[par] = p.hbf + ((size_t)(0 * 2 + par) * 2 + dir) * BATCH * HID;
    h1b[par] = p.hbf + ((size_t)(1 * 2 + par) * 2 + dir) * BATCH * HID;
  }

  const u16* wih = p.wih + (size_t)dir * LAY * G3 * DIN;
  const u16* bri0[3];  // layer-0 Wih rows (x0-GEMM B operand)
  const u16* bri1[3];  // layer-1 Wih rows (x1-GEMM B operand)
  #pragma unroll
  for (int g = 0; g < 3; ++g) {
    bri0[g] = wih + (size_t)(g * HID + j) * DIN;
    bri1[g] = wih + ((size_t)G3 + (size_t)(g * HID + j)) * DIN;
  }

  const float* bih0 = p.bih[dir];
  const float* bhh0 = p.bhh[dir];
  const float* bih1 = bih0 + G3;
  const float* bhh1 = bhh0 + G3;
  const float b0_r  = bih0[j] + bhh0[j];
  const float b0_z  = bih0[HID + j] + bhh0[HID + j];
  const float b0_in = bih0[2 * HID + j];
  const float b0_hn = bhh0[2 * HID + j];
  const float b1_r  = bih1[j] + bhh1[j];
  const float b1_z  = bih1[HID + j] + bhh1[HID + j];
  const float b1_in = bih1[2 * HID + j];
  const float b1_hn = bhh1[2 * HID + j];

  // init h (fp32 masters) + bf16 broadcasts into parity 0 (agent-scope)
  float hreg0[4], hreg1[4];
  #pragma unroll
  for (int i = 0; i < 4; ++i) {
    const int m = wave * 16 + lq * 4 + i;       // C/D row = (lane>>4)*4 + reg
    hreg0[i] = p.enc_h[(size_t)m * (2 * HID) + (size_t)dir * HID + j];
    st_agent_u16(&h0b[0][(size_t)m * HID + j], f2bf(hreg0[i]));
    hreg1[i] = p.enc_h[((size_t)BATCH + m) * (2 * HID) + (size_t)dir * HID + j];
    st_agent_u16(&h1b[0][(size_t)m * HID + j], f2bf(hreg1[i]));
  }

  u32* fown  = p.flags + (size_t)dir * 32;
  u32* fslot = fown + slice;

  __threadfence_block();
  __syncthreads();
  if (threadIdx.x == 0) st_agent_u32(fslot, 1);

  float* hsec = p.out + (size_t)BATCH * SEQ * 2 * HID;

  // ---- precompute accx0 for i=0 (xin needs no sync) ----
  f32x4 accx0[3];
  accx0[0] = f32x4{0, 0, 0, 0}; accx0[1] = accx0[0]; accx0[2] = accx0[0];
  {
    const u16* ax = p.xin + ((size_t)am * SEQ + (dir ? SEQ - 1 : 0)) * DIN;
    #pragma unroll 4
    for (int k0 = 0; k0 < 512; k0 += 32) {
      const int koff = k0 + lq * 8;
      const bf16x8 a_x = *(const bf16x8*)(ax + koff);
      #pragma unroll
      for (int g = 0; g < 3; ++g)
        accx0[g] = __builtin_amdgcn_mfma_f32_16x16x32_bf16(
            a_x, *(const bf16x8*)(bri0[g] + koff), accx0[g], 0, 0, 0);
    }
  }
  poll_ge(fown, 1);  // init broadcasts visible

  for (int i = 0; i <= SEQ; ++i) {
    // ---- fused GEMMs: h0 frags feed L0 h-GEMM AND L1 x-GEMM ----
    const u16* h0r = h0b[i & 1] + (size_t)am * HID;
    const u16* h1r = h1b[(i + 1) & 1] + (size_t)am * HID;  // h1^{(i-1)}
    f32x4 acch0[3], accx1[3], acch1[3];
    acch0[0] = f32x4{0, 0, 0, 0}; acch0[1] = acch0[0]; acch0[2] = acch0[0];
    accx1[0] = acch0[0]; accx1[1] = acch0[0]; accx1[2] = acch0[0];
    acch1[0] = acch0[0]; acch1[1] = acch0[0]; acch1[2] = acch0[0];
    #pragma unroll 4
    for (int k0 = 0; k0 < 512; k0 += 32) {
      const int koff = k0 + lq * 8;
      const bf16x8 a0 = ld_frag_agent(h0r + koff);
      #pragma unroll
      for (int g = 0; g < 3; ++g)
        acch0[g] = __builtin_amdgcn_mfma_f32_16x16x32_bf16(
            a0, *(const bf16x8*)&lwhh[0][g][ln][koff], acch0[g], 0, 0, 0);
      #pragma unroll
      for (int g = 0; g < 3; ++g)
        accx1[g] = __builtin_amdgcn_mfma_f32_16x16x32_bf16(
            a0, *(const bf16x8*)(bri1[g] + koff), accx1[g], 0, 0, 0);
    }
    #pragma unroll 4
    for (int k0 = 0; k0 < 512; k0 += 32) {
      const int koff = k0 + lq * 8;
      const bf16x8 a1 = ld_frag_agent(h1r + koff);  // garbage at i=0, unused
      #pragma unroll
      for (int g = 0; g < 3; ++g)
        acch1[g] = __builtin_amdgcn_mfma_f32_16x16x32_bf16(
            a1, *(const bf16x8*)&lwhh[1][g][ln][koff], acch1[g], 0, 0, 0);
    }

    // ---- L0 epilogue: h0^{(i+1)} ----
    if (i < SEQ) {
      u16* hw = h0b[(i + 1) & 1];
      #pragma unroll
      for (int r = 0; r < 4; ++r) {
        const int m = wave * 16 + lq * 4 + r;
        const float rg = 1.f / (1.f + __expf(-(accx0[0][r] + acch0[0][r] + b0_r)));
        const float zg = 1.f / (1.f + __expf(-(accx0[1][r] + acch0[1][r] + b0_z)));
        const float ng = tanhf(accx0[2][r] + b0_in + rg * (acch0[2][r] + b0_hn));
        const float hnew = (1.f - zg) * ng + zg * hreg0[r];
        hreg0[r] = hnew;
        st_agent_u16(&hw[(size_t)m * HID + j], f2bf(hnew));  // also serves as out0[i]
        if (i == SEQ - 1)
          hsec[(size_t)m * (2 * HID) + (size_t)dir * HID + j] = hnew;
      }
    }

    // ---- L1 epilogue: h1^{(i)} for step t=i-1 ----
    if (i >= 1) {
      const int t  = i - 1;
      const int tt = dir ? (SEQ - 1 - t) : t;
      u16* hw = h1b[i & 1];
      #pragma unroll
      for (int r = 0; r < 4; ++r) {
        const int m = wave * 16 + lq * 4 + r;
        const float rg = 1.f / (1.f + __expf(-(accx1[0][r] + acch1[0][r] + b1_r)));
        const float zg = 1.f / (1.f + __expf(-(accx1[1][r] + acch1[1][r] + b1_z)));
        const float ng = tanhf(accx1[2][r] + b1_in + rg * (acch1[2][r] + b1_hn));
        const float hnew = (1.f - zg) * ng + zg * hreg1[r];
        hreg1[r] = hnew;
        if (i < SEQ) st_agent_u16(&hw[(size_t)m * HID + j], f2bf(hnew));
        p.out[((size_t)m * SEQ + tt) * (2 * HID) + (size_t)dir * HID + j] = hnew;
        if (i == SEQ)
          hsec[((size_t)BATCH + m) * (2 * HID) + (size_t)dir * HID + j] = hnew;
      }
    }

    // ---- signal: all this WG's stores drained, then flag ----
    __threadfence_block();
    __syncthreads();
    if (threadIdx.x == 0) st_agent_u32(fslot, (u32)(i + 2));

    if (i < SEQ) {
      if (i + 1 < SEQ) {
        // ---- x0-GEMM for iter i+1 in the barrier shadow ----
        const int tn = i + 1;
        const u16* ax = p.xin + ((size_t)am * SEQ + (dir ? SEQ - 1 - tn : tn)) * DIN;
        accx0[0] = f32x4{0, 0, 0, 0}; accx0[1] = accx0[0]; accx0[2] = accx0[0];
        #pragma unroll 4
        for (int k0 = 0; k0 < 512; k0 += 32) {
          const int koff = k0 + lq * 8;
          const bf16x8 a_x = *(const bf16x8*)(ax + koff);
          #pragma unroll
          for (int g = 0; g < 3; ++g)
            accx0[g] = __builtin_amdgcn_mfma_f32_16x16x32_bf16(
                a_x, *(const bf16x8*)(bri0[g] + koff), accx0[g], 0, 0, 0);
        }
      }
      poll_ge(fown, (u32)(i + 2));  // all WGs finished iter i
    }
  }
}

extern "C" void kernel_launch(void* const* d_in, const int* in_sizes, int n_in,
                              void* d_out, int out_size, void* d_ws, size_t ws_size,
                              hipStream_t stream) {
  Params p;
  p.input  = (const float*)d_in[0];
  p.enc_h  = (const float*)d_in[1];
  p.Wih[0] = (const float*)d_in[2];
  p.Whh[0] = (const float*)d_in[3];
  p.bih[0] = (const float*)d_in[4];
  p.bhh[0] = (const float*)d_in[5];
  p.Wih[1] = (const float*)d_in[6];
  p.Whh[1] = (const float*)d_in[7];
  p.bih[1] = (const float*)d_in[8];
  p.bhh[1] = (const float*)d_in[9];
  p.out = (float*)d_out;

  uintptr_t base = (uintptr_t)d_ws;
  size_t off = 0;
  auto take = [&](size_t bytes) -> void* {
    void* r = (void*)(base + off);
    off += (bytes + 255) & ~(size_t)255;
    return r;
  };
  p.xin   = (u16*)take((size_t)BATCH * SEQ * DIN * 2);        // 33.6 MB
  p.wih   = (u16*)take((size_t)2 * LAY * G3 * DIN * 2);       //  6.3 MB
  p.whh   = (u16*)take((size_t)2 * LAY * G3 * HID * 2);       //  6.3 MB
  p.hbf   = (u16*)take((size_t)LAY * 2 * 2 * BATCH * HID * 2);//  1.0 MB
  p.flags = (u32*)take((size_t)2 * 32 * 4);                   //  256 B
  if (off > ws_size) return;  // ~47 MB required

  convert_kernel<<<dim3(2048), dim3(256), 0, stream>>>(p);
  recur_all<<<dim3(64), dim3(256), 0, stream>>>(p);
}

// Round 3
// 8404.544 us; speedup vs baseline: 1.5980x; 1.4137x over previous
//
#include <hip/hip_runtime.h>

// Problem dims (fixed)
constexpr int BATCH = 64;
constexpr int SEQ   = 512;
constexpr int DIN   = 512;
constexpr int HID   = 512;
constexpr int LAY   = 2;
constexpr int G3    = 3 * HID;   // 1536
constexpr int KPAD  = 522;       // odd dword stride (261) -> conflict-free LDS rows

typedef __attribute__((ext_vector_type(8))) short bf16x8;  // MFMA A/B frag (4 VGPRs)
typedef __attribute__((ext_vector_type(4))) float f32x4;   // MFMA C/D frag
typedef unsigned short u16;
typedef unsigned int   u32;
typedef unsigned long long u64;

__device__ __forceinline__ u16 f2bf(float f) {
  union { float f; u32 u; } v; v.f = f;
  return (u16)((v.u + 0x7fffu + ((v.u >> 16) & 1u)) >> 16);  // RNE
}

// Agent-scope RELAXED accesses: coherent at LLC (bypass non-coherent per-XCD
// L2), and crucially NO cache maintenance: no buffer_inv (acquire killer),
// no buffer_wbl2 (release killer). Visibility protocol: producer's agent
// stores are drained (vmcnt 0) by __syncthreads before the flag store; LLC is
// the single serialization point; consumer's loads issue after its poll
// branch resolves (waves issue vector-memory ops in order).
__device__ __forceinline__ u64 ld_agent_u64(const u16* p) {
  return __hip_atomic_load((const u64*)p, __ATOMIC_RELAXED, __HIP_MEMORY_SCOPE_AGENT);
}
__device__ __forceinline__ bf16x8 ld_frag_agent(const u16* p) {
  union { u64 q[2]; bf16x8 f; } u;
  u.q[0] = ld_agent_u64(p);
  u.q[1] = ld_agent_u64(p + 4);
  return u.f;
}
__device__ __forceinline__ void st_agent_u16(u16* p, u16 v) {
  __hip_atomic_store(p, v, __ATOMIC_RELAXED, __HIP_MEMORY_SCOPE_AGENT);
}
__device__ __forceinline__ void st_agent_u32(u32* p, u32 v) {
  __hip_atomic_store(p, v, __ATOMIC_RELAXED, __HIP_MEMORY_SCOPE_AGENT);
}

// Poll all 32 flags of a cell (one coalesced 128B load) until min >= target.
__device__ __forceinline__ void poll_ge(const u32* flags, u32 target) {
  const int idx = threadIdx.x & 31;
  for (;;) {
    u32 v = __hip_atomic_load(flags + idx, __ATOMIC_RELAXED, __HIP_MEMORY_SCOPE_AGENT);
    #pragma unroll
    for (int off = 16; off >= 1; off >>= 1) {
      u32 o = (u32)__shfl_xor((int)v, off, 64);
      v = v < o ? v : o;
    }
    if (v >= target) break;
    __builtin_amdgcn_s_sleep(1);
  }
  __asm__ volatile("" ::: "memory");  // keep subsequent loads after the poll
}

struct Params {
  const float* input;     // [BATCH][SEQ][DIN]
  const float* enc_h;     // [LAY][BATCH][2*HID]
  const float* Wih[2];    // dir f/b: [LAY][G3][DIN]
  const float* Whh[2];    // [LAY][G3][HID]
  const float* bih[2];    // [LAY][G3]
  const float* bhh[2];    // [LAY][G3]
  float* out;             // [BATCH][SEQ][2H] ++ [LAY][BATCH][2H]
  u16* xin;               // [BATCH][SEQ][DIN] bf16
  u16* wih;               // [2dir][LAY][G3][DIN] bf16
  u16* whh;               // [2dir][LAY][G3][HID] bf16
  u16* out0;              // [2dir][SEQ][BATCH][HID] bf16 layer-0 outputs (scan order)
  u16* hbf;               // [LAY][2 parity][2 dir][BATCH][HID] bf16 h broadcast
  u32* flags;             // [LAY][2dir][32] per-WG step flags (0=none,1=init,t+2=step t done)
};

__global__ __launch_bounds__(256) void convert_kernel(Params p) {
  const int gtid = blockIdx.x * 256 + threadIdx.x;
  const int nthr = gridDim.x * 256;
  for (int i = gtid; i < BATCH * SEQ * DIN; i += nthr) p.xin[i] = f2bf(p.input[i]);
  for (int d = 0; d < 2; ++d) {
    const float* s1 = p.Wih[d];
    u16* d1 = p.wih + (size_t)d * LAY * G3 * DIN;
    for (int i = gtid; i < LAY * G3 * DIN; i += nthr) d1[i] = f2bf(s1[i]);
    const float* s2 = p.Whh[d];
    u16* d2 = p.whh + (size_t)d * LAY * G3 * HID;
    for (int i = gtid; i < LAY * G3 * HID; i += nthr) d2[i] = f2bf(s2[i]);
  }
  if (gtid < LAY * 2 * 32) p.flags[gtid] = 0;
}

// 128 WGs: wg>>6 = layer (layer1 trails layer0 by one step), wg&1 = dir,
// (wg&63)>>1 = 16-wide hidden slice. 4 waves = 4 batch m-tiles of 16.
// h master fp32 in regs; bf16 double-buffered broadcast via LLC (agent ops).
// Whh slice LDS-resident; Wih/x L1+L2-cached (no cache maintenance anywhere).
// x-GEMM for step t+1 runs between signal(t) and poll(t) — barrier shadow.
// R3 change vs R0: ALL agent-scope payload loads (h frags; layer-1 x frags)
// are register-batched BEFORE their MFMA loop — one latency exposure per
// GEMM instead of ~16 partially-serialized LLC round trips.
__global__ __launch_bounds__(256, 1) void recur_all(Params p) {
  const int wg    = blockIdx.x;     // 0..127
  const int layer = wg >> 6;
  const int cwg   = wg & 63;
  const int dir   = cwg & 1;
  const int slice = cwg >> 1;       // 0..31
  const int j0    = slice * 16;
  const int wave  = threadIdx.x >> 6;
  const int lane  = threadIdx.x & 63;
  const int lq = lane >> 4, ln = lane & 15;
  const int j = j0 + ln;            // hidden column (C/D col = lane&15)

  // ---- stage Whh slice into LDS: [gate][jj][k] (odd-dword row stride) ----
  __shared__ u16 lwhh[3][16][KPAD];   // 50,112 B
  {
    const u16* whh = p.whh + ((size_t)dir * LAY + layer) * G3 * HID;
    for (int idx = threadIdx.x; idx < 3 * 16 * 64; idx += 256) {
      const int k8 = idx & 63, row = idx >> 6;     // row = g*16+jj
      const int g = row >> 4, jj = row & 15;
      *(bf16x8*)&lwhh[g][jj][k8 * 8] =
          *(const bf16x8*)(whh + (size_t)(g * HID + j0 + jj) * HID + k8 * 8);
    }
  }

  u16* hbL = p.hbf + (size_t)layer * 2 * 2 * BATCH * HID;
  u16* hb[2] = { hbL + (size_t)dir * BATCH * HID,
                 hbL + (size_t)(2 + dir) * BATCH * HID };

  const u16* wih = p.wih + ((size_t)dir * LAY + layer) * G3 * DIN;
  const u16* bri[3];
  #pragma unroll
  for (int g = 0; g < 3; ++g) bri[g] = wih + (size_t)(g * HID + j) * DIN;

  const float* bih = p.bih[dir] + (size_t)layer * G3;
  const float* bhh = p.bhh[dir] + (size_t)layer * G3;
  const float b_r  = bih[j] + bhh[j];
  const float b_z  = bih[HID + j] + bhh[HID + j];
  const float bi_n = bih[2 * HID + j];
  const float bh_n = bhh[2 * HID + j];

  // init h (fp32 master) + bf16 broadcast into parity 0 (agent-scope)
  float hreg[4];
  #pragma unroll
  for (int i = 0; i < 4; ++i) {
    const int m = wave * 16 + lq * 4 + i;       // C/D row = (lane>>4)*4 + reg
    hreg[i] = p.enc_h[((size_t)layer * BATCH + m) * (2 * HID) + (size_t)dir * HID + j];
    st_agent_u16(&hb[0][(size_t)m * HID + j], f2bf(hreg[i]));
  }

  u32* fown  = p.flags + (size_t)(layer * 2 + dir) * 32;
  u32* fdep  = p.flags + (size_t)dir * 32;      // layer-0's cell, same dir
  u32* fslot = fown + slice;

  __threadfence_block();   // vmcnt(0)/lgkmcnt(0): LDS staging + init stores drained
  __syncthreads();
  if (threadIdx.x == 0) st_agent_u32(fslot, 1);

  const int am = wave * 16 + ln;                // A-frag row (lane&15 within M-tile)
  float* hsec = p.out + (size_t)BATCH * SEQ * 2 * HID;

  // ---- precompute accx for step 0 (layer 1 must wait for out0[0] first) ----
  f32x4 accx[3];
  if (layer == 1) poll_ge(fdep, 2);
  accx[0] = f32x4{0, 0, 0, 0}; accx[1] = accx[0]; accx[2] = accx[0];
  if (layer == 0) {
    const u16* ax = p.xin + ((size_t)am * SEQ + (dir ? SEQ - 1 : 0)) * DIN;
    #pragma unroll 4
    for (int k0 = 0; k0 < 512; k0 += 32) {
      const int koff = k0 + lq * 8;
      const bf16x8 a_x = *(const bf16x8*)(ax + koff);
      #pragma unroll
      for (int g = 0; g < 3; ++g)
        accx[g] = __builtin_amdgcn_mfma_f32_16x16x32_bf16(
            a_x, *(const bf16x8*)(bri[g] + koff), accx[g], 0, 0, 0);
    }
  } else {
    const u16* ax = p.out0 + ((size_t)dir * SEQ * BATCH + am) * HID;
    bf16x8 fx[16];
    #pragma unroll
    for (int kk = 0; kk < 16; ++kk) fx[kk] = ld_frag_agent(ax + kk * 32 + lq * 8);
    #pragma unroll
    for (int kk = 0; kk < 16; ++kk) {
      const int koff = kk * 32 + lq * 8;
      #pragma unroll
      for (int g = 0; g < 3; ++g)
        accx[g] = __builtin_amdgcn_mfma_f32_16x16x32_bf16(
            fx[kk], *(const bf16x8*)(bri[g] + koff), accx[g], 0, 0, 0);
    }
  }
  poll_ge(fown, 1);  // h_0 broadcast visible

  for (int t = 0; t < SEQ; ++t) {
    // ---- h-GEMM (critical path): batched agent loads, ONE exposure ----
    const u16* ah = hb[t & 1] + (size_t)am * HID;
    bf16x8 fh[16];
    #pragma unroll
    for (int kk = 0; kk < 16; ++kk) fh[kk] = ld_frag_agent(ah + kk * 32 + lq * 8);
    f32x4 acch[3];
    acch[0] = f32x4{0, 0, 0, 0}; acch[1] = acch[0]; acch[2] = acch[0];
    #pragma unroll
    for (int kk = 0; kk < 16; ++kk) {
      const int koff = kk * 32 + lq * 8;
      #pragma unroll
      for (int g = 0; g < 3; ++g)
        acch[g] = __builtin_amdgcn_mfma_f32_16x16x32_bf16(
            fh[kk], *(const bf16x8*)&lwhh[g][ln][koff], acch[g], 0, 0, 0);
    }

    // ---- gate epilogue + stores ----
    u16* hwrite = hb[(t + 1) & 1];
    #pragma unroll
    for (int i = 0; i < 4; ++i) {
      const int m = wave * 16 + lq * 4 + i;
      const float r = 1.f / (1.f + __expf(-(accx[0][i] + acch[0][i] + b_r)));
      const float z = 1.f / (1.f + __expf(-(accx[1][i] + acch[1][i] + b_z)));
      const float n = tanhf(accx[2][i] + bi_n + r * (acch[2][i] + bh_n));
      const float hnew = (1.f - z) * n + z * hreg[i];
      hreg[i] = hnew;
      if (t + 1 < SEQ) st_agent_u16(&hwrite[(size_t)m * HID + j], f2bf(hnew));
      if (layer == 0) {
        st_agent_u16(&p.out0[(((size_t)dir * SEQ + t) * BATCH + m) * HID + j], f2bf(hnew));
      } else {
        const int tt = dir ? (SEQ - 1 - t) : t;
        p.out[((size_t)m * SEQ + tt) * (2 * HID) + (size_t)dir * HID + j] = hnew;
      }
      if (t == SEQ - 1)
        hsec[((size_t)layer * BATCH + m) * (2 * HID) + (size_t)dir * HID + j] = hnew;
    }

    // ---- signal: all this WG's stores drained, then flag (no RMW) ----
    __threadfence_block();
    __syncthreads();
    if (threadIdx.x == 0) st_agent_u32(fslot, (u32)(t + 2));

    if (t + 1 < SEQ) {
      // ---- x-GEMM for t+1 in the barrier shadow ----
      if (layer == 1) poll_ge(fdep, (u32)(t + 3));  // out0[t+1] ready
      const int tn = t + 1;
      accx[0] = f32x4{0, 0, 0, 0}; accx[1] = accx[0]; accx[2] = accx[0];
      if (layer == 0) {
        const u16* ax = p.xin + ((size_t)am * SEQ + (dir ? SEQ - 1 - tn : tn)) * DIN;
        #pragma unroll 4
        for (int k0 = 0; k0 < 512; k0 += 32) {
          const int koff = k0 + lq * 8;
          const bf16x8 a_x = *(const bf16x8*)(ax + koff);
          #pragma unroll
          for (int g = 0; g < 3; ++g)
            accx[g] = __builtin_amdgcn_mfma_f32_16x16x32_bf16(
                a_x, *(const bf16x8*)(bri[g] + koff), accx[g], 0, 0, 0);
        }
      } else {
        const u16* ax = p.out0 + (((size_t)dir * SEQ + tn) * BATCH + am) * HID;
        bf16x8 fx[16];
        #pragma unroll
        for (int kk = 0; kk < 16; ++kk) fx[kk] = ld_frag_agent(ax + kk * 32 + lq * 8);
        #pragma unroll
        for (int kk = 0; kk < 16; ++kk) {
          const int koff = kk * 32 + lq * 8;
          #pragma unroll
          for (int g = 0; g < 3; ++g)
            accx[g] = __builtin_amdgcn_mfma_f32_16x16x32_bf16(
                fx[kk], *(const bf16x8*)(bri[g] + koff), accx[g], 0, 0, 0);
        }
      }
      poll_ge(fown, (u32)(t + 2));  // h_{t+1} broadcast visible
    }
  }
}

extern "C" void kernel_launch(void* const* d_in, const int* in_sizes, int n_in,
                              void* d_out, int out_size, void* d_ws, size_t ws_size,
                              hipStream_t stream) {
  Params p;
  p.input  = (const float*)d_in[0];
  p.enc_h  = (const float*)d_in[1];
  p.Wih[0] = (const float*)d_in[2];
  p.Whh[0] = (const float*)d_in[3];
  p.bih[0] = (const float*)d_in[4];
  p.bhh[0] = (const float*)d_in[5];
  p.Wih[1] = (const float*)d_in[6];
  p.Whh[1] = (const float*)d_in[7];
  p.bih[1] = (const float*)d_in[8];
  p.bhh[1] = (const float*)d_in[9];
  p.out = (float*)d_out;

  uintptr_t base = (uintptr_t)d_ws;
  size_t off = 0;
  auto take = [&](size_t bytes) -> void* {
    void* r = (void*)(base + off);
    off += (bytes + 255) & ~(size_t)255;
    return r;
  };
  p.xin   = (u16*)take((size_t)BATCH * SEQ * DIN * 2);        // 33.6 MB
  p.wih   = (u16*)take((size_t)2 * LAY * G3 * DIN * 2);       //  6.3 MB
  p.whh   = (u16*)take((size_t)2 * LAY * G3 * HID * 2);       //  6.3 MB
  p.out0  = (u16*)take((size_t)2 * SEQ * BATCH * HID * 2);    // 67.1 MB
  p.hbf   = (u16*)take((size_t)LAY * 2 * 2 * BATCH * HID * 2);//  1.0 MB
  p.flags = (u32*)take((size_t)LAY * 2 * 32 * 4);             //  512 B
  if (off > ws_size) return;  // ~114 MB required

  convert_kernel<<<dim3(2048), dim3(256), 0, stream>>>(p);
  recur_all<<<dim3(128), dim3(256), 0, stream>>>(p);
}

// Round 4
// 6874.834 us; speedup vs baseline: 1.9536x; 1.2225x over previous
//
#include <hip/hip_runtime.h>

// Problem dims (fixed)
constexpr int BATCH = 64;
constexpr int SEQ   = 512;
constexpr int DIN   = 512;
constexpr int HID   = 512;
constexpr int LAY   = 2;
constexpr int G3    = 3 * HID;   // 1536
constexpr int KPAD  = 522;       // odd dword stride -> conflict-free LDS rows (Whh)
constexpr int SLOTS = SEQ + 1;   // out0 ring: slot 0 = init h, slot t+1 = h after step t
constexpr int HPAD  = 520;       // hstage row stride in u16 (1040 B, bank-friendly)

typedef __attribute__((ext_vector_type(8))) short bf16x8;  // MFMA A/B frag (4 VGPRs)
typedef __attribute__((ext_vector_type(4))) float f32x4;   // MFMA C/D frag
typedef unsigned short u16;
typedef unsigned int   u32;
typedef unsigned long long u64;

__device__ __forceinline__ u16 f2bf(float f) {
  union { float f; u32 u; } v; v.f = f;
  return (u16)((v.u + 0x7fffu + ((v.u >> 16) & 1u)) >> 16);  // RNE
}

// Agent-scope RELAXED accesses: coherent at LLC (bypass non-coherent per-XCD
// L2), no cache maintenance. Producer sc1 stores are drained (vmcnt 0) by
// __syncthreads before the flag store; LLC is the serialization point.
// KEY INVARIANT for the plain-load paths below: every out0 ring slot is
// written EXACTLY ONCE per dispatch, and always via sc1 stores (which bypass
// all L2s). A consumer's L2 therefore can never hold a stale copy of a line
// it has never read -> after the flag poll, PLAIN cached loads are safe and
// get L2 reuse. Only the layer-1 h parity buffer (rewritten every 2 steps)
// still requires sc1 loads.
__device__ __forceinline__ u64 ld_agent_u64(const u16* p) {
  return __hip_atomic_load((const u64*)p, __ATOMIC_RELAXED, __HIP_MEMORY_SCOPE_AGENT);
}
__device__ __forceinline__ void st_agent_u16(u16* p, u16 v) {
  __hip_atomic_store(p, v, __ATOMIC_RELAXED, __HIP_MEMORY_SCOPE_AGENT);
}
__device__ __forceinline__ void st_agent_u32(u32* p, u32 v) {
  __hip_atomic_store(p, v, __ATOMIC_RELAXED, __HIP_MEMORY_SCOPE_AGENT);
}

// Poll all 32 flags of one cell (coalesced 128B) until min >= target.
__device__ __forceinline__ void poll_ge(const u32* flags, u32 target) {
  const int idx = threadIdx.x & 31;
  for (;;) {
    u32 v = __hip_atomic_load(flags + idx, __ATOMIC_RELAXED, __HIP_MEMORY_SCOPE_AGENT);
    #pragma unroll
    for (int off = 16; off >= 1; off >>= 1) {
      u32 o = (u32)__shfl_xor((int)v, off, 64);
      v = v < o ? v : o;
    }
    if (v >= target) break;
    __builtin_amdgcn_s_sleep(1);
  }
  __asm__ volatile("" ::: "memory");
}

// Combined poll (layer 1): lanes 0-31 watch dep cell (layer 0, same dir),
// lanes 32-63 watch own cell. One load instr, two 128B segments.
__device__ __forceinline__ void poll_both(const u32* flags, int dir, u32 tdep, u32 town) {
  const int l = threadIdx.x & 63;
  const u32* addr = flags + (size_t)dir * 32 + (l & 31) + ((l >> 5) * 64);
  const u32 tgt = (l < 32) ? tdep : town;
  for (;;) {
    u32 v = __hip_atomic_load(addr, __ATOMIC_RELAXED, __HIP_MEMORY_SCOPE_AGENT);
    if (__all((int)(v >= tgt))) break;
    __builtin_amdgcn_s_sleep(1);
  }
  __asm__ volatile("" ::: "memory");
}

struct Params {
  const float* input;     // [BATCH][SEQ][DIN]
  const float* enc_h;     // [LAY][BATCH][2*HID]
  const float* Wih[2];    // dir f/b: [LAY][G3][DIN]
  const float* Whh[2];    // [LAY][G3][HID]
  const float* bih[2];    // [LAY][G3]
  const float* bhh[2];    // [LAY][G3]
  float* out;             // [BATCH][SEQ][2H] ++ [LAY][BATCH][2H]
  u16* xin;               // [BATCH][SEQ][DIN] bf16
  u16* wih;               // [2dir][LAY][G3][DIN] bf16
  u16* whh;               // [2dir][LAY][G3][HID] bf16
  u16* out0;              // [2dir][SLOTS][BATCH][HID] bf16 L0 h ring (slot 0 = init)
  u16* hbf;               // [2 parity][2 dir][BATCH][HID] bf16 L1 h broadcast
  u32* flags;             // [LAY*2 cells][32] per-WG step flags
};

__global__ __launch_bounds__(256) void convert_kernel(Params p) {
  const int gtid = blockIdx.x * 256 + threadIdx.x;
  const int nthr = gridDim.x * 256;
  for (int i = gtid; i < BATCH * SEQ * DIN; i += nthr) p.xin[i] = f2bf(p.input[i]);
  for (int d = 0; d < 2; ++d) {
    const float* s1 = p.Wih[d];
    u16* d1 = p.wih + (size_t)d * LAY * G3 * DIN;
    for (int i = gtid; i < LAY * G3 * DIN; i += nthr) d1[i] = f2bf(s1[i]);
    const float* s2 = p.Whh[d];
    u16* d2 = p.whh + (size_t)d * LAY * G3 * HID;
    for (int i = gtid; i < LAY * G3 * HID; i += nthr) d2[i] = f2bf(s2[i]);
  }
  if (gtid < LAY * 2 * 32) p.flags[gtid] = 0;
}

// 128 WGs: wg>>6 = layer, wg&1 = dir, (wg&63)>>1 = 16-wide hidden slice.
// 4 waves = 4 batch m-tiles of 16. Flags/signals unchanged from the proven
// R0 skeleton. R4 changes: (1) out0 is a (SEQ+1)-slot single-write ring ->
// L0's h-A-tile and L1's x-tile are PLAIN cached loads (L2 reuse, no MALL
// scatter); L0's hb buffer deleted. (2) L1's h parity tile is staged via
// CONTIGUOUS sc1 loads into padded LDS (8x128B segments/instr vs 16x64B
// scattered), reads via bank-free ds_read_b128. (3) L1's two polls merged.
__global__ __launch_bounds__(256, 1) void recur_all(Params p) {
  const int wg    = blockIdx.x;     // 0..127
  const int layer = wg >> 6;
  const int cwg   = wg & 63;
  const int dir   = cwg & 1;
  const int slice = cwg >> 1;       // 0..31
  const int j0    = slice * 16;
  const int wave  = threadIdx.x >> 6;
  const int lane  = threadIdx.x & 63;
  const int lq = lane >> 4, ln = lane & 15;
  const int j = j0 + ln;            // hidden column (C/D col = lane&15)

  __shared__ u16 lwhh[3][16][KPAD];     // 50,112 B (Whh slice)
  __shared__ u16 hstage[BATCH][HPAD];   // 66,560 B (L1 h tile stage)

  // ---- stage Whh slice into LDS ----
  {
    const u16* whh = p.whh + ((size_t)dir * LAY + layer) * G3 * HID;
    for (int idx = threadIdx.x; idx < 3 * 16 * 64; idx += 256) {
      const int k8 = idx & 63, row = idx >> 6;     // row = g*16+jj
      const int g = row >> 4, jj = row & 15;
      *(bf16x8*)&lwhh[g][jj][k8 * 8] =
          *(const bf16x8*)(whh + (size_t)(g * HID + j0 + jj) * HID + k8 * 8);
    }
  }

  u16* o0 = p.out0 + (size_t)dir * SLOTS * BATCH * HID;   // this dir's L0 ring
  u16* hb[2] = { p.hbf + (size_t)dir * BATCH * HID,
                 p.hbf + (size_t)(2 + dir) * BATCH * HID };  // L1 parity

  const u16* wih = p.wih + ((size_t)dir * LAY + layer) * G3 * DIN;
  const u16* bri[3];
  #pragma unroll
  for (int g = 0; g < 3; ++g) bri[g] = wih + (size_t)(g * HID + j) * DIN;

  const float* bih = p.bih[dir] + (size_t)layer * G3;
  const float* bhh = p.bhh[dir] + (size_t)layer * G3;
  const float b_r  = bih[j] + bhh[j];
  const float b_z  = bih[HID + j] + bhh[HID + j];
  const float bi_n = bih[2 * HID + j];
  const float bh_n = bhh[2 * HID + j];

  // init h (fp32 master) + bf16 broadcast (L0 -> ring slot 0, L1 -> parity 0)
  float hreg[4];
  #pragma unroll
  for (int i = 0; i < 4; ++i) {
    const int m = wave * 16 + lq * 4 + i;       // C/D row = (lane>>4)*4 + reg
    hreg[i] = p.enc_h[((size_t)layer * BATCH + m) * (2 * HID) + (size_t)dir * HID + j];
    if (layer == 0) st_agent_u16(&o0[(size_t)m * HID + j], f2bf(hreg[i]));
    else            st_agent_u16(&hb[0][(size_t)m * HID + j], f2bf(hreg[i]));
  }

  u32* fown  = p.flags + (size_t)(layer * 2 + dir) * 32;
  u32* fslot = fown + slice;
  u32* fdep  = p.flags + (size_t)dir * 32;      // layer-0's cell, same dir

  __threadfence_block();
  __syncthreads();
  if (threadIdx.x == 0) st_agent_u32(fslot, 1);

  const int am = wave * 16 + ln;                // A-frag row (batch index)
  float* hsec = p.out + (size_t)BATCH * SEQ * 2 * HID;

  if (layer == 0) {
    // ================= LAYER 0 =================
    // x-GEMM step 0 (xin, no dependency)
    f32x4 accx[3];
    accx[0] = f32x4{0, 0, 0, 0}; accx[1] = accx[0]; accx[2] = accx[0];
    {
      const u16* ax = p.xin + ((size_t)am * SEQ + (dir ? SEQ - 1 : 0)) * DIN;
      #pragma unroll 4
      for (int k0 = 0; k0 < 512; k0 += 32) {
        const int koff = k0 + lq * 8;
        const bf16x8 a_x = *(const bf16x8*)(ax + koff);
        #pragma unroll
        for (int g = 0; g < 3; ++g)
          accx[g] = __builtin_amdgcn_mfma_f32_16x16x32_bf16(
              a_x, *(const bf16x8*)(bri[g] + koff), accx[g], 0, 0, 0);
      }
    }
    poll_ge(fown, 1);  // ring slot 0 visible

    for (int t = 0; t < SEQ; ++t) {
      // h-GEMM: A = ring slot t, PLAIN cached loads (single-write slot)
      const u16* ah = o0 + (size_t)t * BATCH * HID + (size_t)am * HID;
      f32x4 acch[3];
      acch[0] = f32x4{0, 0, 0, 0}; acch[1] = acch[0]; acch[2] = acch[0];
      #pragma unroll 4
      for (int k0 = 0; k0 < 512; k0 += 32) {
        const int koff = k0 + lq * 8;
        const bf16x8 a_h = *(const bf16x8*)(ah + koff);
        #pragma unroll
        for (int g = 0; g < 3; ++g)
          acch[g] = __builtin_amdgcn_mfma_f32_16x16x32_bf16(
              a_h, *(const bf16x8*)&lwhh[g][ln][koff], acch[g], 0, 0, 0);
      }

      // epilogue -> ring slot t+1 (sc1 stores)
      u16* ow = o0 + (size_t)(t + 1) * BATCH * HID;
      #pragma unroll
      for (int i = 0; i < 4; ++i) {
        const int m = wave * 16 + lq * 4 + i;
        const float r = 1.f / (1.f + __expf(-(accx[0][i] + acch[0][i] + b_r)));
        const float z = 1.f / (1.f + __expf(-(accx[1][i] + acch[1][i] + b_z)));
        const float n = tanhf(accx[2][i] + bi_n + r * (acch[2][i] + bh_n));
        const float hnew = (1.f - z) * n + z * hreg[i];
        hreg[i] = hnew;
        st_agent_u16(&ow[(size_t)m * HID + j], f2bf(hnew));
        if (t == SEQ - 1)
          hsec[(size_t)m * (2 * HID) + (size_t)dir * HID + j] = hnew;
      }

      __threadfence_block();
      __syncthreads();
      if (threadIdx.x == 0) st_agent_u32(fslot, (u32)(t + 2));

      if (t + 1 < SEQ) {
        // x-GEMM for t+1 in the barrier shadow
        const int tn = t + 1;
        const u16* ax = p.xin + ((size_t)am * SEQ + (dir ? SEQ - 1 - tn : tn)) * DIN;
        accx[0] = f32x4{0, 0, 0, 0}; accx[1] = accx[0]; accx[2] = accx[0];
        #pragma unroll 4
        for (int k0 = 0; k0 < 512; k0 += 32) {
          const int koff = k0 + lq * 8;
          const bf16x8 a_x = *(const bf16x8*)(ax + koff);
          #pragma unroll
          for (int g = 0; g < 3; ++g)
            accx[g] = __builtin_amdgcn_mfma_f32_16x16x32_bf16(
                a_x, *(const bf16x8*)(bri[g] + koff), accx[g], 0, 0, 0);
        }
        poll_ge(fown, (u32)(t + 2));  // slot t+1 fully written
      }
    }
  } else {
    // ================= LAYER 1 =================
    f32x4 accx[3];
    accx[0] = f32x4{0, 0, 0, 0}; accx[1] = accx[0]; accx[2] = accx[0];
    poll_ge(fdep, 2);   // ring slot 1 ready (L0 step 0 done)
    {
      // x-GEMM step 0: PLAIN cached loads from ring slot 1
      const u16* ax = o0 + (size_t)1 * BATCH * HID + (size_t)am * HID;
      #pragma unroll 4
      for (int k0 = 0; k0 < 512; k0 += 32) {
        const int koff = k0 + lq * 8;
        const bf16x8 a_x = *(const bf16x8*)(ax + koff);
        #pragma unroll
        for (int g = 0; g < 3; ++g)
          accx[g] = __builtin_amdgcn_mfma_f32_16x16x32_bf16(
              a_x, *(const bf16x8*)(bri[g] + koff), accx[g], 0, 0, 0);
      }
    }
    poll_ge(fown, 1);   // parity-0 h broadcast visible

    // stage hb[0] -> LDS (contiguous sc1 loads, 16B/thread x 16 iters)
    {
      const u16* src = hb[0];
      u64 q0[16], q1[16];
      #pragma unroll
      for (int it = 0; it < 16; ++it) {
        const u16* sp = src + ((size_t)(it * 256) + threadIdx.x) * 8;
        q0[it] = ld_agent_u64(sp);
        q1[it] = ld_agent_u64(sp + 4);
      }
      #pragma unroll
      for (int it = 0; it < 16; ++it) {
        const int flat = it * 256 + threadIdx.x;    // 16B unit index
        u64* dp = (u64*)&hstage[flat >> 6][(flat & 63) * 8];
        dp[0] = q0[it]; dp[1] = q1[it];
      }
    }

    for (int t = 0; t < SEQ; ++t) {
      __syncthreads();   // staged h tile visible to all waves

      // h-GEMM: A from padded LDS (bank-free b128), B from lwhh
      f32x4 acch[3];
      acch[0] = f32x4{0, 0, 0, 0}; acch[1] = acch[0]; acch[2] = acch[0];
      #pragma unroll
      for (int kk = 0; kk < 16; ++kk) {
        const int koff = kk * 32 + lq * 8;
        const bf16x8 a_h = *(const bf16x8*)&hstage[am][koff];
        #pragma unroll
        for (int g = 0; g < 3; ++g)
          acch[g] = __builtin_amdgcn_mfma_f32_16x16x32_bf16(
              a_h, *(const bf16x8*)&lwhh[g][ln][koff], acch[g], 0, 0, 0);
      }

      // epilogue: parity write (sc1) + final output (plain fp32)
      u16* hwrite = hb[(t + 1) & 1];
      const int tt = dir ? (SEQ - 1 - t) : t;
      #pragma unroll
      for (int i = 0; i < 4; ++i) {
        const int m = wave * 16 + lq * 4 + i;
        const float r = 1.f / (1.f + __expf(-(accx[0][i] + acch[0][i] + b_r)));
        const float z = 1.f / (1.f + __expf(-(accx[1][i] + acch[1][i] + b_z)));
        const float n = tanhf(accx[2][i] + bi_n + r * (acch[2][i] + bh_n));
        const float hnew = (1.f - z) * n + z * hreg[i];
        hreg[i] = hnew;
        if (t + 1 < SEQ) st_agent_u16(&hwrite[(size_t)m * HID + j], f2bf(hnew));
        p.out[((size_t)m * SEQ + tt) * (2 * HID) + (size_t)dir * HID + j] = hnew;
        if (t == SEQ - 1)
          hsec[((size_t)BATCH + m) * (2 * HID) + (size_t)dir * HID + j] = hnew;
      }

      __threadfence_block();
      __syncthreads();
      if (threadIdx.x == 0) st_agent_u32(fslot, (u32)(t + 2));

      if (t + 1 < SEQ) {
        const int tn = t + 1;
        // one combined poll: L0 wrote slot tn+1 (dep>=tn+2) AND own cell
        // finished t (own>=t+2 -> h parity (t+1)&1 complete)
        poll_both(p.flags, dir, (u32)(tn + 2), (u32)(t + 2));

        // issue next h-tile stage loads (sc1, contiguous) ...
        const u16* src = hb[(t + 1) & 1];
        u64 q0[16], q1[16];
        #pragma unroll
        for (int it = 0; it < 16; ++it) {
          const u16* sp = src + ((size_t)(it * 256) + threadIdx.x) * 8;
          q0[it] = ld_agent_u64(sp);
          q1[it] = ld_agent_u64(sp + 4);
        }

        // ... x-GEMM for tn overlaps their latency (plain loads, slot tn+1)
        const u16* ax = o0 + (size_t)(tn + 1) * BATCH * HID + (size_t)am * HID;
        accx[0] = f32x4{0, 0, 0, 0}; accx[1] = accx[0]; accx[2] = accx[0];
        #pragma unroll 4
        for (int k0 = 0; k0 < 512; k0 += 32) {
          const int koff = k0 + lq * 8;
          const bf16x8 a_x = *(const bf16x8*)(ax + koff);
          #pragma unroll
          for (int g = 0; g < 3; ++g)
            accx[g] = __builtin_amdgcn_mfma_f32_16x16x32_bf16(
                a_x, *(const bf16x8*)(bri[g] + koff), accx[g], 0, 0, 0);
        }

        // land staged tile in LDS (prev h-GEMM reads ended before signal bar)
        #pragma unroll
        for (int it = 0; it < 16; ++it) {
          const int flat = it * 256 + threadIdx.x;
          u64* dp = (u64*)&hstage[flat >> 6][(flat & 63) * 8];
          dp[0] = q0[it]; dp[1] = q1[it];
        }
      }
    }
  }
}

extern "C" void kernel_launch(void* const* d_in, const int* in_sizes, int n_in,
                              void* d_out, int out_size, void* d_ws, size_t ws_size,
                              hipStream_t stream) {
  Params p;
  p.input  = (const float*)d_in[0];
  p.enc_h  = (const float*)d_in[1];
  p.Wih[0] = (const float*)d_in[2];
  p.Whh[0] = (const float*)d_in[3];
  p.bih[0] = (const float*)d_in[4];
  p.bhh[0] = (const float*)d_in[5];
  p.Wih[1] = (const float*)d_in[6];
  p.Whh[1] = (const float*)d_in[7];
  p.bih[1] = (const float*)d_in[8];
  p.bhh[1] = (const float*)d_in[9];
  p.out = (float*)d_out;

  uintptr_t base = (uintptr_t)d_ws;
  size_t off = 0;
  auto take = [&](size_t bytes) -> void* {
    void* r = (void*)(base + off);
    off += (bytes + 255) & ~(size_t)255;
    return r;
  };
  p.xin   = (u16*)take((size_t)BATCH * SEQ * DIN * 2);         // 33.6 MB
  p.wih   = (u16*)take((size_t)2 * LAY * G3 * DIN * 2);        //  6.3 MB
  p.whh   = (u16*)take((size_t)2 * LAY * G3 * HID * 2);        //  6.3 MB
  p.out0  = (u16*)take((size_t)2 * SLOTS * BATCH * HID * 2);   // 67.2 MB
  p.hbf   = (u16*)take((size_t)2 * 2 * BATCH * HID * 2);       //  0.5 MB
  p.flags = (u32*)take((size_t)LAY * 2 * 32 * 4);              //  512 B
  if (off > ws_size) return;  // ~114 MB required (same budget as before)

  convert_kernel<<<dim3(2048), dim3(256), 0, stream>>>(p);
  recur_all<<<dim3(128), dim3(256), 0, stream>>>(p);
}